// Round 3
// baseline (117.013 us; speedup 1.0000x reference)
//
#include <hip/hip_runtime.h>
#include <hip/hip_bf16.h>

#define EPSW 1e-6f

typedef __attribute__((ext_vector_type(4))) float floatx4;
typedef __attribute__((ext_vector_type(8))) short shortx8;   // 8 bf16 (4 VGPRs)

// round-to-nearest-even float -> bf16 bits (finite inputs)
__device__ __forceinline__ unsigned short f2bf(float f) {
    unsigned int u = __float_as_uint(f);
    u = (u + 0x7fffu + ((u >> 16) & 1u)) >> 16;
    return (unsigned short)u;
}

// pack 8 fp32 -> 8 bf16 (round-half-up: +0x8000 then take hi16 via v_perm).
// Error <= 0.5 ulp (rne except ties) — well inside the 5x absmax margin.
__device__ __forceinline__ shortx8 pack8(floatx4 a, floatx4 b) {
    union { shortx8 v; unsigned int u[4]; } r;
    const unsigned a0 = __float_as_uint(a.x) + 0x8000u, a1 = __float_as_uint(a.y) + 0x8000u;
    const unsigned a2 = __float_as_uint(a.z) + 0x8000u, a3 = __float_as_uint(a.w) + 0x8000u;
    const unsigned b0 = __float_as_uint(b.x) + 0x8000u, b1 = __float_as_uint(b.y) + 0x8000u;
    const unsigned b2 = __float_as_uint(b.z) + 0x8000u, b3 = __float_as_uint(b.w) + 0x8000u;
    r.u[0] = __builtin_amdgcn_perm(a1, a0, 0x07060302u);  // (bf(a.y)<<16)|bf(a.x)
    r.u[1] = __builtin_amdgcn_perm(a3, a2, 0x07060302u);
    r.u[2] = __builtin_amdgcn_perm(b1, b0, 0x07060302u);
    r.u[3] = __builtin_amdgcn_perm(b3, b2, 0x07060302u);
    return r.v;
}

// ---------------------------------------------------------------------------
// prep_small: 33 blocks.
//   blocks 0..31: wt transform. W (128 x 2000 fp32) -> wt bf16 in MFMA
//                 B-fragment layout [kg][h][8], kg = k/8, K padded to 2048
//                 (kg 250..255 zero). Block handles 1024 granules.
//   block 32    : A (normalized adjacency) and Mt = (A@A)^T -> global.
// ---------------------------------------------------------------------------
__global__ __launch_bounds__(256) void prep_small(const float* __restrict__ W,
                                                  const int* __restrict__ ei,
                                                  const float* __restrict__ ew,
                                                  unsigned short* __restrict__ wt,
                                                  float* __restrict__ Mt) {
    const int bid = blockIdx.x;
    const int t   = threadIdx.x;
    if (bid < 32) {
#pragma unroll
        for (int i = 0; i < 4; ++i) {
            const int G  = bid * 1024 + i * 256 + t;   // 0..32767
            const int kg = G >> 7;
            const int h  = G & 127;
            const int k  = kg * 8;
            floatx4 v0 = (floatx4){0.f, 0.f, 0.f, 0.f};
            floatx4 v1 = (floatx4){0.f, 0.f, 0.f, 0.f};
            if (k < 2000) {  // kg<=249 -> whole granule valid
                v0 = *(const floatx4*)(W + (size_t)h * 2000 + k);
                v1 = *(const floatx4*)(W + (size_t)h * 2000 + k + 4);
            }
            unsigned short* p = wt + ((size_t)kg * 128 + h) * 8;
            p[0] = f2bf(v0.x); p[1] = f2bf(v0.y); p[2] = f2bf(v0.z); p[3] = f2bf(v0.w);
            p[4] = f2bf(v1.x); p[5] = f2bf(v1.y); p[6] = f2bf(v1.z); p[7] = f2bf(v1.w);
        }
    } else {
        __shared__ float A[4096];
        __shared__ float deg[64];
        __shared__ float dinv[64];
        if (t < 64) deg[t] = 1.0f;             // self-loop pre-added
        for (int i = t; i < 4096; i += 256) A[i] = 0.0f;
        __syncthreads();
        const int* src = ei;
        const int* dst = ei + 4096;
        for (int e = t; e < 4096; e += 256) {
            float w = ew[e];
            w = (w <= 0.0f) ? EPSW : w;
            atomicAdd(&deg[dst[e]], w);
        }
        __syncthreads();
        if (t < 64) dinv[t] = 1.0f / sqrtf(deg[t]);
        __syncthreads();
        for (int e = t; e < 4096; e += 256) {
            float w = ew[e];
            w = (w <= 0.0f) ? EPSW : w;
            const int s = src[e], d = dst[e];
            atomicAdd(&A[d * 64 + s], dinv[s] * w * dinv[d]);
        }
        if (t < 64) atomicAdd(&A[t * 64 + t], dinv[t] * dinv[t]);
        __syncthreads();
        // Mt[c][n] = (A@A)[n][c]
#pragma unroll
        for (int i = 0; i < 16; ++i) {
            const int idx = i * 256 + t;
            const int n = idx >> 6, c = idx & 63;
            float s = 0.0f;
#pragma unroll 8
            for (int k = 0; k < 64; ++k) s += A[n * 64 + k] * A[k * 64 + c];
            Mt[c * 64 + n] = s;
        }
    }
}

// ---------------------------------------------------------------------------
// gemm_direct: z[r][h] = sum_k x[r][k]*W[h][k].  No LDS, no barriers,
// no workspace staging of x. Grid (8, 32): block = (rt*2+hh, batch).
// Wave w owns one 16x16 tile: rows b*64+rt*16..+16, h-tile hh*4+w.
// A-frags: 2 coalesced float4 loads straight from x + inline bf16 pack
// (one a-frag per k-step, shared across the wave's whole tile; the 4 waves
// of a block share rows -> L1 absorbs the redundancy; the hh pair of blocks
// is adjacent in blockIdx.x -> second x read hits L3).
// B-frags: 16B loads from pre-baked wt (L2-resident, zero-padded K).
// 2 accumulators (s&1) break the MFMA dependency chain.
// ---------------------------------------------------------------------------
__global__ __launch_bounds__(256) void gemm_direct(const float* __restrict__ x,
                                                   const unsigned short* __restrict__ wt,
                                                   float* __restrict__ z) {
    const int t    = threadIdx.x;
    const int wave = t >> 6, lane = t & 63;
    const int m = lane & 15, q = lane >> 4;
    const int b  = blockIdx.y;
    const int rt = blockIdx.x >> 1, hh = blockIdx.x & 1;
    const float* xrow = x + (size_t)(b * 64 + rt * 16 + m) * 2000;
    const int htile = hh * 4 + wave;
    const shortx8* Bg = (const shortx8*)wt;
    const int gb = q * 128 + htile * 16 + m;   // wt granule index; +512 per k-step

    floatx4 acc0 = (floatx4){0.f, 0.f, 0.f, 0.f};
    floatx4 acc1 = (floatx4){0.f, 0.f, 0.f, 0.f};
#pragma unroll 9
    for (int s = 0; s < 63; ++s) {           // k = s*32 .. +32, covers 2000 (pad 2016)
        const int k0 = s * 32 + q * 8;
        floatx4 f0 = (floatx4){0.f, 0.f, 0.f, 0.f};
        floatx4 f1 = (floatx4){0.f, 0.f, 0.f, 0.f};
        if (k0 < 2000)     f0 = *(const floatx4*)(xrow + k0);
        if (k0 + 4 < 2000) f1 = *(const floatx4*)(xrow + k0 + 4);
        const shortx8 af = pack8(f0, f1);
        const shortx8 bf = Bg[gb + s * 512];
        if (s & 1) acc1 = __builtin_amdgcn_mfma_f32_16x16x32_bf16(af, bf, acc1, 0, 0, 0);
        else       acc0 = __builtin_amdgcn_mfma_f32_16x16x32_bf16(af, bf, acc0, 0, 0, 0);
    }
    // C/D layout: row = q*4+v, col = m
#pragma unroll
    for (int v = 0; v < 4; ++v)
        z[(size_t)(b * 64 + rt * 16 + q * 4 + v) * 128 + htile * 16 + m] = acc0[v] + acc1[v];
}

// ---------------------------------------------------------------------------
// apply_M: y[b][n][h] = bias[h] + sum_m M[n][m] * z[b*64+m][h]
// Grid (32 b, 8 h-chunks of 16) x 256 thr. Mt indexing (Mt[m*64+n]) makes the
// per-instr LDS pattern 4 distinct banks x 16-lane broadcast: conflict-free.
// ---------------------------------------------------------------------------
__global__ __launch_bounds__(256) void apply_M(const float* __restrict__ z,
                                               const float* __restrict__ Mtg,
                                               const float* __restrict__ bias,
                                               float* __restrict__ y) {
    __shared__ float Ms[4096];
    __shared__ float zs[64][16];
    const int b  = blockIdx.x;
    const int hc = blockIdx.y;
    const int t  = threadIdx.x;
#pragma unroll
    for (int i = 0; i < 16; ++i) Ms[i * 256 + t] = Mtg[i * 256 + t];
#pragma unroll
    for (int i = 0; i < 4; ++i) {
        const int idx = i * 256 + t;
        const int mr = idx >> 4, hh = idx & 15;
        zs[mr][hh] = z[(size_t)(b * 64 + mr) * 128 + hc * 16 + hh];
    }
    __syncthreads();
    const int h  = t & 15;
    const int n0 = (t >> 4) * 4;
    const float bv = bias[hc * 16 + h];
    float s0 = bv, s1 = bv, s2 = bv, s3 = bv;
#pragma unroll
    for (int mm = 0; mm < 64; ++mm) {
        const float zv = zs[mm][h];
        s0 += Ms[mm * 64 + n0 + 0] * zv;
        s1 += Ms[mm * 64 + n0 + 1] * zv;
        s2 += Ms[mm * 64 + n0 + 2] * zv;
        s3 += Ms[mm * 64 + n0 + 3] * zv;
    }
    float* yp = y + (size_t)b * 8192 + (size_t)n0 * 128 + hc * 16 + h;
    yp[0]   = s0;
    yp[128] = s1;
    yp[256] = s2;
    yp[384] = s3;
}

extern "C" void kernel_launch(void* const* d_in, const int* in_sizes, int n_in,
                              void* d_out, int out_size, void* d_ws, size_t ws_size,
                              hipStream_t stream) {
    const float* x    = (const float*)d_in[0];   // (2048, 2000) fp32
    const int*   ei   = (const int*)d_in[1];     // (2, 4096)
    const float* ew   = (const float*)d_in[2];   // (4096,)
    const float* W    = (const float*)d_in[3];   // (128, 2000) fp32
    const float* bias = (const float*)d_in[4];   // (128,)
    float* y = (float*)d_out;                    // (32, 64, 128) fp32

    float* z  = (float*)d_ws;                    // 262144 f (1 MB)
    float* Mt = z + 262144;                      // 4096 f
    unsigned short* wt = (unsigned short*)(Mt + 4096);   // 256*128*8 bf16 (512 KB)

    prep_small<<<33, 256, 0, stream>>>(W, ei, ew, wt, Mt);
    gemm_direct<<<dim3(8, 32), 256, 0, stream>>>(x, wt, z);
    apply_M<<<dim3(32, 8), 256, 0, stream>>>(z, Mt, bias, y);
}